// Round 1
// baseline (189.340 us; speedup 1.0000x reference)
//
#include <hip/hip_runtime.h>

// Batched autocorrelation, X:[4096,8192] f32 -> out:[4096,64] f32.
// Per-row correlation as bf16 MFMA Gram matrices:
//   X_i[m] = x[32 i + m];  G_d[m][n] = sum_i X_i[m] * X_{i+d}[n], d=0..2
//   R_{32q+s} = sum_{m+s<32} G_q[m][m+s] + sum_{m+s>=32} G_{q+1}[m][m+s-32]
// Centering folded in algebraically (fp32):
//   C_k = R_k - mu*(2S - P_k - Q_k) + (T-k) mu^2 ;  out = C_k / C_0
//
// R3 (this version):
//   * 1.00x read amplification: the old e8/e9 loads (p[256],p[288]) duplicated
//     another lane's e0/e1. u4 == pack(e8,e9) is obtained by a cross-half
//     __shfl_xor(32) of u0 (sh=0 lanes take u0 of lane+32, same chunk;
//     sh=1 lanes take u0 of lane-32, NEXT chunk) -> explicit 1-deep prefetch
//     pipeline carries next chunk's e0..e7. 8 loads/chunk instead of 10.
//   * Software RNE pack2bf (~11 VALU) replaced by 1-instr v_cvt_pk_bf16_f32
//     (default MODE.round = RNE, bit-matches the old pack on normal floats).
//   * Main loop per chunk: 8 coalesced dword loads, 8 f32 adds, 4 cvt_pk,
//     4 alignbit, 1 cndmask + 1 shfl, 3 MFMA.
// LDS is only a 6.5 KB/wave bf16 G-dump for the diagonal-band reduction.
// Occupancy: 256 thr/block, <=128 VGPR -> 4 blocks/CU = 16 waves/CU.

typedef __bf16 bf16x8 __attribute__((ext_vector_type(8)));
typedef float f32x16 __attribute__((ext_vector_type(16)));
typedef unsigned int uint32;

#define T_LEN 8192
#define WPB 4                       // waves (rows) per block
#define GB_STRIDE 34                // shorts per G row (+2 pad)
#define GB_SHORTS (96 * GB_STRIDE)  // 3 matrices x 32 rows = 6528 B / wave

__device__ __forceinline__ uint32 cvtpk(float lo, float hi) { // (lo, hi) RNE
  uint32 r;
  asm("v_cvt_pk_bf16_f32 %0, %1, %2" : "=v"(r) : "v"(lo), "v"(hi));
  return r;
}
__device__ __forceinline__ short f2bf(float f) {
  uint32 u = __builtin_bit_cast(uint32, f);
  return (short)((u + 0x7fffu + ((u >> 16) & 1u)) >> 16);
}
__device__ __forceinline__ float bf2f(short h) {
  uint32 u = ((uint32)(unsigned short)h) << 16;
  return __builtin_bit_cast(float, u);
}

__global__ __launch_bounds__(WPB * 64, 4)
void autocorr_kernel(const float* __restrict__ X, float* __restrict__ out, int nrows) {
  __shared__ short gb_all[WPB * GB_SHORTS];
  const int wave = threadIdx.x >> 6;
  const int lane = threadIdx.x & 63;
  const int row = blockIdx.x * WPB + wave;
  if (row >= nrows) return;               // no barriers anywhere: waves independent
  short* gb = gb_all + wave * GB_SHORTS;

  const int m = lane & 31;                // A-role row m / B-role col n
  const int sh = lane >> 5;               // K-half s
  const float* __restrict__ base = X + (size_t)row * T_LEN + (sh << 8) + m;

  f32x16 g0 = {}, g1 = {}, g2 = {};
  float ssum = 0.f;

  // prologue: chunk 0's e0..e7 (each load: 32 consecutive floats per half -> coalesced)
  float e0 = base[0],   e1 = base[32],  e2 = base[64],  e3 = base[96];
  float e4 = base[128], e5 = base[160], e6 = base[192], e7 = base[224];
  uint32 u0 = cvtpk(e0, e1);

#pragma unroll 4
  for (int c = 0; c < 16; ++c) {
    // ---- prefetch chunk c+1 (skipped for c==15: zeros, matches OOB masking) ----
    float n0 = 0.f, n1 = 0.f, n2 = 0.f, n3 = 0.f;
    float n4 = 0.f, n5 = 0.f, n6 = 0.f, n7 = 0.f;
    if (c < 15) {
      const float* pn = base + ((c + 1) << 9);
      n0 = pn[0];   n1 = pn[32];  n2 = pn[64];  n3 = pn[96];
      n4 = pn[128]; n5 = pn[160]; n6 = pn[192]; n7 = pn[224];
    }

    // ---- compute on chunk c (values carried from previous iteration) ----
    ssum += ((e0 + e1) + (e2 + e3)) + ((e4 + e5) + (e6 + e7));
    uint32 u1 = cvtpk(e2, e3), u2 = cvtpk(e4, e5), u3 = cvtpk(e6, e7);
    uint32 u0n = cvtpk(n0, n1);           // next chunk's u0 (0 when c==15)
    // u4 = pack(e8,e9): sh=0 needs u0 of lane+32 (cur chunk);
    //                   sh=1 needs u0 of lane-32 (next chunk).
    uint32 u4 = (uint32)__shfl_xor((int)(sh ? u0 : u0n), 32, 64);

    int4 a4 = make_int4((int)u0, (int)u1, (int)u2, (int)u3);
    int4 b1;
    b1.x = (int)((u0 >> 16) | (u1 << 16));
    b1.y = (int)((u1 >> 16) | (u2 << 16));
    b1.z = (int)((u2 >> 16) | (u3 << 16));
    b1.w = (int)((u3 >> 16) | (u4 << 16));
    int4 b2 = make_int4((int)u1, (int)u2, (int)u3, (int)u4);
    bf16x8 fa = __builtin_bit_cast(bf16x8, a4);
    bf16x8 f1 = __builtin_bit_cast(bf16x8, b1);
    bf16x8 f2 = __builtin_bit_cast(bf16x8, b2);
    g0 = __builtin_amdgcn_mfma_f32_32x32x16_bf16(fa, fa, g0, 0, 0, 0);
    g1 = __builtin_amdgcn_mfma_f32_32x32x16_bf16(fa, f1, g1, 0, 0, 0);
    g2 = __builtin_amdgcn_mfma_f32_32x32x16_bf16(fa, f2, g2, 0, 0, 0);

    // rotate pipeline registers (pure renaming under unroll)
    e0 = n0; e1 = n1; e2 = n2; e3 = n3; e4 = n4; e5 = n5; e6 = n6; e7 = n7;
    u0 = u0n;
  }

  for (int d = 32; d > 0; d >>= 1) ssum += __shfl_xor(ssum, d, 64);

  // ---- dump G to LDS in bf16 (6.5 KB/wave) ----
#pragma unroll
  for (int v = 0; v < 16; ++v) {
    int rm = (v & 3) + (sh << 2) + ((v >> 2) << 3); // C/D row; col = m
    gb[(rm)      * GB_STRIDE + m] = f2bf(g0[v]);
    gb[(32 + rm) * GB_STRIDE + m] = f2bf(g1[v]);
    gb[(64 + rm) * GB_STRIDE + m] = f2bf(g2[v]);
  }

  // ---- diagonal-band sums: lane handles lag k = lane+1 ----
  int k = lane + 1;
  int s2 = k & 31, q = k >> 5;
  float ck = 0.f;
#pragma unroll 4
  for (int mm = 0; mm < 32; ++mm) {
    int ms = mm + s2;
    int dd = q + (ms >> 5);
    ck += bf2f(gb[(dd * 32 + mm) * GB_STRIDE + (ms & 31)]);
  }
  float c0 = 0.f;
#pragma unroll 4
  for (int mm = 0; mm < 32; ++mm) c0 += bf2f(gb[mm * GB_STRIDE + mm]); // broadcast

  // ---- centering correction: prefix (P_k) / suffix (Q_k) scans over lanes ----
  float P = X[(size_t)row * T_LEN + lane];
  float Q = X[(size_t)row * T_LEN + (T_LEN - 1 - lane)];
  for (int d = 1; d < 64; d <<= 1) {
    float tp = __shfl_up(P, (unsigned)d, 64);
    float tq = __shfl_up(Q, (unsigned)d, 64);
    if (lane >= d) { P += tp; Q += tq; }
  }
  float mu = ssum * (1.0f / (float)T_LEN);
  float Ck = ck - mu * (2.f * ssum - P - Q) + (float)(T_LEN - k) * mu * mu;
  float C0 = c0 - mu * 2.f * ssum + (float)T_LEN * mu * mu;
  out[(size_t)row * 64 + lane] = Ck / C0;
}

extern "C" void kernel_launch(void* const* d_in, const int* in_sizes, int n_in,
                              void* d_out, int out_size, void* d_ws, size_t ws_size,
                              hipStream_t stream) {
  const float* X = (const float*)d_in[0];
  float* out = (float*)d_out;
  int nrows = in_sizes[0] / T_LEN;  // 4096
  dim3 grid((nrows + WPB - 1) / WPB);
  autocorr_kernel<<<grid, dim3(WPB * 64), 0, stream>>>(X, out, nrows);
}